// Round 16
// baseline (609.341 us; speedup 1.0000x reference)
//
#include <hip/hip_runtime.h>
#include <hip/hip_bf16.h>
#include <math.h>

#define NN 100000
#define EE 1600000
#define OUTC 40
#define NB 391            // (NN+255)/256
#define NG 6250           // NN/16 groups for attn/ffn
#define CAP 64            // bucket capacity per node (deg ~ Poisson(16))
#define NBIN 391          // bins of 256 nodes
#define BCAP 6144         // edges per bin capacity (E[X]=4194, sigma=65)
#define GB 1563           // (NN+63)/64 token/h0 blocks
#define GG 25000          // gather blocks (wave per node)

// prepacked-weight offsets (in shorts), padded to LDS strides
#define WP_WIN 0          // 64 x 264   (Win 64x256)
#define WP_SG  16896      // 3 x 64 x 72 (sgW 3x64x64)
#define WP_QKV 30720      // 192 x 72
#define WP_WO  44544      // 64 x 72
#define WP_W1  49152      // 128 x 72
#define WP_W2  58368      // 64 x 136  (W2 64x128)
#define WP_WC  67072      // 48 x 72  (rows 40-47 zeroed)
#define WP_TOT 70528

typedef __hip_bfloat16 bf16;
typedef __attribute__((ext_vector_type(8))) short bf16x8;
typedef __attribute__((ext_vector_type(4))) float f32x4;

__device__ __forceinline__ unsigned short f2us(float f){
  bf16 b = __float2bfloat16(f);
  unsigned short u; __builtin_memcpy(&u, &b, 2); return u;
}
__device__ __forceinline__ float us2f(unsigned short u){
  union{unsigned x; float f;} c; c.x = ((unsigned)u)<<16; return c.f;
}
__device__ __forceinline__ float lo_f(unsigned u){ union{unsigned x;float f;}c; c.x = u<<16; return c.f; }
__device__ __forceinline__ float hi_f(unsigned u){ union{unsigned x;float f;}c; c.x = u & 0xffff0000u; return c.f; }

// branch-free exact-erf gelu (A&S 7.1.26, |erf err| <= 1.5e-7)
__device__ __forceinline__ float gelu_f(float v){
  float ax = fabsf(v);
  float t  = __builtin_amdgcn_rcpf(fmaf(0.3275911f, ax, 1.0f));
  float p  = fmaf(t, 1.061405429f, -1.453152027f);
  p = fmaf(t, p, 1.421413741f);
  p = fmaf(t, p, -0.284496736f);
  p = fmaf(t, p, 0.254829592f);
  p = p * t;
  float ex = __expf(-ax*ax);
  float er = fmaf(-p, ex, 1.0f);       // erf(|v|)
  er = copysignf(er, v);
  return 0.5f * v * (1.0f + er);
}

// ---------------- prep: {zero binFill || weight prepack} ----------------
__global__ void k_prep0(const float* __restrict__ Win, const float* __restrict__ sgW,
                        const float* __restrict__ Wqkv, const float* __restrict__ Wo,
                        const float* __restrict__ W1, const float* __restrict__ W2,
                        const float* __restrict__ Wc, unsigned short* __restrict__ wp,
                        int* __restrict__ binFill){
  if (blockIdx.x < 2){
    int i = blockIdx.x*256 + threadIdx.x;
    if (i < NBIN) binFill[i] = 0;
    return;
  }
  const int bid = blockIdx.x - 2;
  for (int idx = bid*256 + threadIdx.x; idx < WP_TOT; idx += 128*256){
    float v; int o;
    if (idx < WP_SG){ o = idx; int r=o/264, c=o-r*264; v = (c<256)? Win[r*256+c] : 0.f; }
    else if (idx < WP_QKV){ o = idx-WP_SG; int h=o/4608, rem=o-h*4608, r=rem/72, c=rem-r*72;
      v=(c<64)? sgW[h*4096+r*64+c] : 0.f; }
    else if (idx < WP_WO){ o = idx-WP_QKV; int r=o/72, c=o-r*72; v=(c<64)? Wqkv[r*64+c]:0.f; }
    else if (idx < WP_W1){ o = idx-WP_WO; int r=o/72, c=o-r*72; v=(c<64)? Wo[r*64+c]:0.f; }
    else if (idx < WP_W2){ o = idx-WP_W1; int r=o/72, c=o-r*72; v=(c<64)? W1[r*64+c]:0.f; }
    else if (idx < WP_WC){ o = idx-WP_W2; int r=o/136, c=o-r*136; v=(c<128)? W2[r*128+c]:0.f; }
    else { o = idx-WP_WC; int r=o/72, c=o-r*72; v=(r<OUTC && c<64)? Wc[r*64+c]:0.f; }
    wp[idx] = f2us(v);
  }
}

// ---------------- CSR pass 1: bin edges (packed int: src | dl<<24) ----------------
__global__ void __launch_bounds__(256) k_bin(const int* __restrict__ ei,
    int* __restrict__ binFill, int* __restrict__ binned){
  __shared__ int hist[NBIN], sbase[NBIN], loc[NBIN];
  const int tid = threadIdx.x;
  const int CH = (EE + gridDim.x - 1) / gridDim.x;
  const int e0 = blockIdx.x * CH;
  const int e1 = min(e0 + CH, EE);
  for (int i = tid; i < NBIN; i += 256){ hist[i] = 0; loc[i] = 0; }
  __syncthreads();
  for (int e = e0 + tid; e < e1; e += 256)
    atomicAdd(&hist[ei[EE + e] >> 8], 1);
  __syncthreads();
  for (int i = tid; i < NBIN; i += 256)
    sbase[i] = atomicAdd(&binFill[i], hist[i]);
  __syncthreads();
  for (int e = e0 + tid; e < e1; e += 256){
    int d = ei[EE + e];
    int s = ei[e];
    int b = d >> 8;
    int p = sbase[b] + atomicAdd(&loc[b], 1);
    if (p < BCAP) binned[(size_t)b*BCAP + p] = s | ((d & 255) << 24);
  }
}

// ---------------- bucket body (CSR pass 2) ----------------
__device__ __forceinline__ void bucket_body(const int* __restrict__ binFill,
    const int* __restrict__ binned, int* __restrict__ srcb,
    int* __restrict__ cnt, float* __restrict__ dinv, int* lcnt, int b){
  const int tid = threadIdx.x;
  lcnt[tid] = 0;
  __syncthreads();
  int m = binFill[b]; if (m > BCAP) m = BCAP;
  const int* seg = binned + (size_t)b*BCAP;
  for (int e = tid; e < m; e += 256){
    int v = seg[e];
    int dl = ((unsigned)v) >> 24;
    int s = v & 0xFFFFFF;
    int p = atomicAdd(&lcnt[dl], 1);
    if (p < CAP) srcb[((size_t)(b << 8) + dl)*CAP + p] = s;
  }
  __syncthreads();
  int d = (b << 8) + tid;
  if (d < NN){
    int c = lcnt[tid];
    dinv[d] = rsqrtf((float)c + 1.0f);
    cnt[d] = min(c, CAP);
  }
}

// ---------------- h0 body: relu(x @ Win^T + b) -> tok0 and p0 ----------------
// Win B-fragments read directly from the global wp image; only X staged in LDS.
__device__ __forceinline__ void h0_body(const float* __restrict__ x,
    const unsigned short* __restrict__ wp, const float* __restrict__ bin,
    unsigned short* __restrict__ tok0, unsigned short* __restrict__ p0,
    unsigned short* Xs, float* bs, int bid){
  const int tid = threadIdx.x;
  const unsigned short* Wg = wp + WP_WIN;
  const int n0 = bid * 64;
  for (int idx = tid; idx < 4096; idx += 256){       // X tile: 64x256, fp32->bf16
    int r = idx >> 6, c0 = (idx & 63) * 4;
    int n = n0 + r; if (n >= NN) n = NN-1;
    float4 v = *(const float4*)(x + (size_t)n*256 + c0);
    unsigned short* d = &Xs[r*264 + c0];
    d[0]=f2us(v.x); d[1]=f2us(v.y); d[2]=f2us(v.z); d[3]=f2us(v.w);
  }
  if (tid < 64) bs[tid] = bin[tid];
  __syncthreads();
  const int w = tid >> 6, lane = tid & 63, quad = lane >> 4, c = lane & 15;
  f32x4 acc[4] = {{0,0,0,0},{0,0,0,0},{0,0,0,0},{0,0,0,0}};
  #pragma unroll
  for (int ks = 0; ks < 8; ++ks){
    int k0 = ks*32 + quad*8;
    bf16x8 a = *(const bf16x8*)&Xs[(w*16 + c)*264 + k0];
    #pragma unroll
    for (int nt = 0; nt < 4; ++nt){
      bf16x8 b = *(const bf16x8*)&Wg[(nt*16 + c)*264 + k0];
      acc[nt] = __builtin_amdgcn_mfma_f32_16x16x32_bf16(a, b, acc[nt], 0,0,0);
    }
  }
  __syncthreads();
  #pragma unroll
  for (int nt = 0; nt < 4; ++nt){
    int col = nt*16 + c;
    float bb = bs[col];
    #pragma unroll
    for (int rg = 0; rg < 4; ++rg){
      int rloc = w*16 + quad*4 + rg;
      Xs[rloc*72 + col] = f2us(fmaxf(acc[nt][rg] + bb, 0.f));
    }
  }
  __syncthreads();
  for (int idx = tid; idx < 512; idx += 256){
    int r = idx >> 3, ch = idx & 7;
    int n = n0 + r;
    if (n < NN){
      uint4 v = *(const uint4*)&Xs[r*72 + ch*8];
      *(uint4*)(tok0 + (size_t)n*64 + ch*8) = v;
      *(uint4*)(p0   + (size_t)n*64 + ch*8) = v;
    }
  }
}

// ---------------- merged: {bucket || h0} ----------------
__global__ void __launch_bounds__(256) k_buckh0(const int* __restrict__ binFill,
    const int* __restrict__ binned, int* __restrict__ srcb,
    int* __restrict__ cnt, float* __restrict__ dinv,
    const float* __restrict__ x, const unsigned short* __restrict__ wp,
    const float* __restrict__ bin, unsigned short* __restrict__ tok0,
    unsigned short* __restrict__ p0){
  __shared__ __align__(16) unsigned short Xs[64*264];
  __shared__ float bs[64];
  __shared__ int lcnt[256];
  if (blockIdx.x < NBIN)
    bucket_body(binFill, binned, srcb, cnt, dinv, lcnt, blockIdx.x);
  else
    h0_body(x, wp, bin, tok0, p0, Xs, bs, blockIdx.x - NBIN);
}

// ---------------- gather body: cur = S @ prev (full-MLP, 8 lanes/edge) ----------
#define GACC(r, wt) \
  a0 += lo_f((r).x)*(wt); a1 += hi_f((r).x)*(wt); \
  a2 += lo_f((r).y)*(wt); a3 += hi_f((r).y)*(wt); \
  a4 += lo_f((r).z)*(wt); a5 += hi_f((r).z)*(wt); \
  a6 += lo_f((r).w)*(wt); a7 += hi_f((r).w)*(wt);

__device__ __forceinline__ void gather_body(const int* __restrict__ cnt,
    const int* __restrict__ srcb, const float* __restrict__ dinv,
    const unsigned short* __restrict__ prev, unsigned short* __restrict__ cur,
    int bid){
  int wid = (bid << 2) + (threadIdx.x >> 6);
  if (wid >= NN) return;
  const int lane = threadIdx.x & 63;
  const int grp = lane >> 3, cl = lane & 7;     // 8 groups x 8 lanes
  const int n = wid;
  const int deg = cnt[n];                        // wave-uniform
  const int* bk = srcb + (size_t)n*CAP;
  const float dn = dinv[n];
  uint4 sr = *(const uint4*)(prev + ((size_t)n << 6) + (cl << 3));
  int sv[8];
  #pragma unroll
  for (int j = 0; j < 8; ++j){
    sv[j] = n;
    if (j*8 < deg){
      int idx = j*8 + grp;
      if (idx < deg) sv[j] = bk[idx];
    }
  }
  float wv[8];
  #pragma unroll
  for (int j = 0; j < 8; ++j){
    wv[j] = 0.f;
    if (j*8 < deg){
      int idx = j*8 + grp;
      if (idx < deg) wv[j] = dinv[sv[j]] * dn;
    }
  }
  uint4 rr[8];
  #pragma unroll
  for (int j = 0; j < 8; ++j){
    if (j*8 < deg)
      rr[j] = *(const uint4*)(prev + ((size_t)sv[j] << 6) + (cl << 3));
  }
  float a0=0,a1=0,a2=0,a3=0,a4=0,a5=0,a6=0,a7=0;
  #pragma unroll
  for (int j = 0; j < 8; ++j){
    if (j*8 < deg){ GACC(rr[j], wv[j]); }
  }
  a0 += __shfl_xor(a0,8); a0 += __shfl_xor(a0,16); a0 += __shfl_xor(a0,32);
  a1 += __shfl_xor(a1,8); a1 += __shfl_xor(a1,16); a1 += __shfl_xor(a1,32);
  a2 += __shfl_xor(a2,8); a2 += __shfl_xor(a2,16); a2 += __shfl_xor(a2,32);
  a3 += __shfl_xor(a3,8); a3 += __shfl_xor(a3,16); a3 += __shfl_xor(a3,32);
  a4 += __shfl_xor(a4,8); a4 += __shfl_xor(a4,16); a4 += __shfl_xor(a4,32);
  a5 += __shfl_xor(a5,8); a5 += __shfl_xor(a5,16); a5 += __shfl_xor(a5,32);
  a6 += __shfl_xor(a6,8); a6 += __shfl_xor(a6,16); a6 += __shfl_xor(a6,32);
  a7 += __shfl_xor(a7,8); a7 += __shfl_xor(a7,16); a7 += __shfl_xor(a7,32);
  if (lane < 8){
    float d2 = dn*dn;
    GACC(sr, d2);
    uint4 pk;
    pk.x = (unsigned)f2us(a0) | ((unsigned)f2us(a1) << 16);
    pk.y = (unsigned)f2us(a2) | ((unsigned)f2us(a3) << 16);
    pk.z = (unsigned)f2us(a4) | ((unsigned)f2us(a5) << 16);
    pk.w = (unsigned)f2us(a6) | ((unsigned)f2us(a7) << 16);
    *(uint4*)(cur + ((size_t)n << 6) + (cl << 3)) = pk;
  }
}

__global__ void __launch_bounds__(256) k_gather(const int* __restrict__ cnt,
    const int* __restrict__ srcb, const float* __restrict__ dinv,
    const unsigned short* __restrict__ prev, unsigned short* __restrict__ cur){
  gather_body(cnt, srcb, dinv, prev, cur, blockIdx.x);
}

// ---------------- token body: relu(cur @ sgW^T + sgb) -> tok ----------------
__device__ __forceinline__ void tok_body(const unsigned short* __restrict__ cur,
    const unsigned short* __restrict__ wsg, const float* __restrict__ sgb,
    unsigned short* __restrict__ tok,
    unsigned short* Xs, unsigned short* Ws, float* bs, int bid){
  const int tid = threadIdx.x;
  {
    const uint4* src = (const uint4*)wsg;
    for (int idx = tid; idx < 576; idx += 256) ((uint4*)Ws)[idx] = src[idx];
  }
  if (tid < 64) bs[tid] = sgb[tid];
  const int n0 = bid*64;
  for (int idx = tid; idx < 512; idx += 256){
    int r = idx >> 3, ch = idx & 7;
    int n = n0 + r; if (n >= NN) n = NN-1;
    *(uint4*)&Xs[r*72 + ch*8] = *(const uint4*)(cur + (size_t)n*64 + ch*8);
  }
  __syncthreads();
  const int w = tid >> 6, lane = tid & 63, quad = lane >> 4, c = lane & 15;
  f32x4 acc[4] = {{0,0,0,0},{0,0,0,0},{0,0,0,0},{0,0,0,0}};
  #pragma unroll
  for (int ks = 0; ks < 2; ++ks){
    int k0 = ks*32 + quad*8;
    bf16x8 a = *(const bf16x8*)&Xs[(w*16 + c)*72 + k0];
    #pragma unroll
    for (int nt = 0; nt < 4; ++nt){
      bf16x8 b = *(const bf16x8*)&Ws[(nt*16 + c)*72 + k0];
      acc[nt] = __builtin_amdgcn_mfma_f32_16x16x32_bf16(a, b, acc[nt], 0,0,0);
    }
  }
  __syncthreads();
  #pragma unroll
  for (int nt = 0; nt < 4; ++nt){
    int col = nt*16 + c;
    float bb = bs[col];
    #pragma unroll
    for (int rg = 0; rg < 4; ++rg){
      int rloc = w*16 + quad*4 + rg;
      Xs[rloc*72 + col] = f2us(fmaxf(acc[nt][rg] + bb, 0.f));
    }
  }
  __syncthreads();
  for (int idx = tid; idx < 512; idx += 256){
    int r = idx >> 3, ch = idx & 7;
    int n = n0 + r;
    if (n < NN)
      *(uint4*)(tok + (size_t)n*64 + ch*8) = *(const uint4*)&Xs[r*72 + ch*8];
  }
}

// ---------------- merged: {token || gather} ----------------
__global__ void __launch_bounds__(256) k_tokgather(
    const unsigned short* __restrict__ tcur, const unsigned short* __restrict__ wsg,
    const float* __restrict__ sgb, unsigned short* __restrict__ tok,
    const int* __restrict__ cnt, const int* __restrict__ srcb,
    const float* __restrict__ dinv, const unsigned short* __restrict__ prev,
    unsigned short* __restrict__ cur){
  __shared__ __align__(16) unsigned short Xs[64*72];
  __shared__ __align__(16) unsigned short Ws[64*72];
  __shared__ float bs[64];
  if (blockIdx.x < GB)
    tok_body(tcur, wsg, sgb, tok, Xs, Ws, bs, blockIdx.x);
  else
    gather_body(cnt, srcb, dinv, prev, cur, blockIdx.x - GB);
}

// ---------------- merged: {token2 || token3} ----------------
__global__ void __launch_bounds__(256) k_tok23(
    const unsigned short* __restrict__ curA, const unsigned short* __restrict__ wsgA,
    const float* __restrict__ sgbA, unsigned short* __restrict__ tokA,
    const unsigned short* __restrict__ curB, const unsigned short* __restrict__ wsgB,
    const float* __restrict__ sgbB, unsigned short* __restrict__ tokOutB){
  __shared__ __align__(16) unsigned short Xs[64*72];
  __shared__ __align__(16) unsigned short Ws[64*72];
  __shared__ float bs[64];
  if (blockIdx.x < GB)
    tok_body(curA, wsgA, sgbA, tokA, Xs, Ws, bs, blockIdx.x);
  else
    tok_body(curB, wsgB, sgbB, tokOutB, Xs, Ws, bs, blockIdx.x - GB);
}

// ---------------- attention + LN1 (persistent) ----------------
// R13 structure restored (all 12 QKV tiles up-front for max MFMA ILP;
// V-deferral regressed per-iter time 1.6x in R14). Xs read-only per iter;
// P@V + LN1 into Ps. No forced occupancy.
__global__ void __launch_bounds__(256) k_attn(unsigned short* __restrict__ tokB,
    const unsigned short* __restrict__ wp, const float* __restrict__ bqkv,
    const float* __restrict__ bo, const float* __restrict__ ln1w,
    const float* __restrict__ ln1b){
  __shared__ __align__(16) unsigned short Xs[64*72];
  __shared__ __align__(16) unsigned short Ps[64*72];
  __shared__ float bq[192], bos[64], l1w[64], l1b[64];
  const int tid = threadIdx.x;
  if (tid < 192) bq[tid] = bqkv[tid];
  if (tid < 64){ bos[tid]=bo[tid]; l1w[tid]=ln1w[tid]; l1b[tid]=ln1b[tid]; }
  const int w = tid >> 6, lane = tid & 63, quad = lane >> 4, c = lane & 15;
  const int rw = w*16;
  const unsigned short* Wq  = wp + WP_QKV;
  const unsigned short* Wos = wp + WP_WO;
  for (int g = blockIdx.x; g < NG; g += gridDim.x){
    __syncthreads();        // protect Xs/Ps from previous iteration readers
    for (int idx = tid; idx < 512; idx += 256){     // stage 64 rows of bf16 tokens
      int r = idx >> 3, ch = idx & 7;
      int t = r & 3, n = g*16 + (r >> 2);           // row = node_local*4 + t
      *(uint4*)&Xs[r*72 + ch*8] = *(const uint4*)(tokB + ((size_t)t*NN + n)*64 + ch*8);
    }
    __syncthreads();
    bf16x8 a0 = *(const bf16x8*)&Xs[(rw+c)*72 + quad*8];
    bf16x8 a1 = *(const bf16x8*)&Xs[(rw+c)*72 + 32 + quad*8];
    f32x4 qk[12];   // 0-3: q tiles, 4-7: k tiles, 8-11: v tiles
    #pragma unroll
    for (int nt = 0; nt < 12; ++nt){
      f32x4 acc = {0,0,0,0};
      bf16x8 b0 = *(const bf16x8*)&Wq[(nt*16+c)*72 + quad*8];
      bf16x8 b1 = *(const bf16x8*)&Wq[(nt*16+c)*72 + 32 + quad*8];
      acc = __builtin_amdgcn_mfma_f32_16x16x32_bf16(a0, b0, acc, 0,0,0);
      acc = __builtin_amdgcn_mfma_f32_16x16x32_bf16(a1, b1, acc, 0,0,0);
      float bb = bq[nt*16 + c];
      acc[0]+=bb; acc[1]+=bb; acc[2]+=bb; acc[3]+=bb;
      qk[nt] = acc;
    }
    float sc[4][4];
    #pragma unroll
    for (int s = 0; s < 4; ++s){
      #pragma unroll
      for (int t = 0; t < 4; ++t){
        float p = qk[0][s]*qk[4][t] + qk[1][s]*qk[5][t]
                + qk[2][s]*qk[6][t] + qk[3][s]*qk[7][t];
        p += __shfl_xor(p, 1); p += __shfl_xor(p, 2);
        p += __shfl_xor(p, 4); p += __shfl_xor(p, 8);
        sc[s][t] = p * 0.125f;
      }
    }
    float pm[4][4];
    #pragma unroll
    for (int s = 0; s < 4; ++s){
      float m = fmaxf(fmaxf(sc[s][0],sc[s][1]), fmaxf(sc[s][2],sc[s][3]));
      float e0=__expf(sc[s][0]-m), e1=__expf(sc[s][1]-m);
      float e2=__expf(sc[s][2]-m), e3=__expf(sc[s][3]-m);
      float inv = 1.f/(e0+e1+e2+e3);
      pm[s][0]=e0*inv; pm[s][1]=e1*inv; pm[s][2]=e2*inv; pm[s][3]=e3*inv;
    }
    // P@V -> Ps in A-layout (wave-private rows; Xs untouched)
    #pragma unroll
    for (int tile = 0; tile < 4; ++tile){
      #pragma unroll
      for (int s = 0; s < 4; ++s){
        float av = pm[s][0]*qk[8+tile][0] + pm[s][1]*qk[8+tile][1]
                 + pm[s][2]*qk[8+tile][2] + pm[s][3]*qk[8+tile][3];
        Ps[(rw + quad*4 + s)*72 + tile*16 + c] = f2us(av);
      }
    }
    bf16x8 p0 = *(const bf16x8*)&Ps[(rw+c)*72 + quad*8];
    bf16x8 p1 = *(const bf16x8*)&Ps[(rw+c)*72 + 32 + quad*8];
    f32x4 ov[4];
    #pragma unroll
    for (int nt = 0; nt < 4; ++nt){
      f32x4 acc = {0,0,0,0};
      bf16x8 b0 = *(const bf16x8*)&Wos[(nt*16+c)*72 + quad*8];
      bf16x8 b1 = *(const bf16x8*)&Wos[(nt*16+c)*72 + 32 + quad*8];
      acc = __builtin_amdgcn_mfma_f32_16x16x32_bf16(p0, b0, acc, 0,0,0);
      acc = __builtin_amdgcn_mfma_f32_16x16x32_bf16(p1, b1, acc, 0,0,0);
      ov[nt] = acc;
    }
    float r4[4][4];
    #pragma unroll
    for (int nt = 0; nt < 4; ++nt){
      int col = nt*16 + c;
      float bb = bos[col];
      #pragma unroll
      for (int rg = 0; rg < 4; ++rg){
        float seqv = us2f(Xs[(rw + quad*4 + rg)*72 + col]);   // residual from intact Xs
        r4[nt][rg] = ov[nt][rg] + bb + seqv;
      }
    }
    #pragma unroll
    for (int rg = 0; rg < 4; ++rg){
      float sm = r4[0][rg]+r4[1][rg]+r4[2][rg]+r4[3][rg];
      sm += __shfl_xor(sm,1); sm += __shfl_xor(sm,2);
      sm += __shfl_xor(sm,4); sm += __shfl_xor(sm,8);
      float mean = sm * (1.f/64.f);
      float d0=r4[0][rg]-mean, d1=r4[1][rg]-mean, d2=r4[2][rg]-mean, d3=r4[3][rg]-mean;
      float vs = d0*d0+d1*d1+d2*d2+d3*d3;
      vs += __shfl_xor(vs,1); vs += __shfl_xor(vs,2);
      vs += __shfl_xor(vs,4); vs += __shfl_xor(vs,8);
      float rinv = rsqrtf(vs*(1.f/64.f) + 1e-5f);
      int row = rw + quad*4 + rg;
      #pragma unroll
      for (int nt = 0; nt < 4; ++nt){
        int col = nt*16 + c;
        Ps[row*72 + col] = f2us((r4[nt][rg] - mean) * rinv * l1w[col] + l1b[col]);
      }
    }
    __syncthreads();
    for (int idx = tid; idx < 512; idx += 256){     // coalesced copy-out from Ps
      int r = idx >> 3, ch = idx & 7;
      int t = r & 3, n = g*16 + (r >> 2);
      *(uint4*)(tokB + ((size_t)t*NN + n)*64 + ch*8) = *(const uint4*)&Ps[r*72 + ch*8];
    }
  }
}

// ---------------- FFN + LN2 + mean + classifier (persistent) ----------------
__global__ void __launch_bounds__(256) k_ffn(const unsigned short* __restrict__ tokB,
    const unsigned short* __restrict__ wp,
    const float* __restrict__ b1, const float* __restrict__ b2,
    const float* __restrict__ ln2w, const float* __restrict__ ln2b,
    const float* __restrict__ bc, float* __restrict__ out){
  __shared__ __align__(16) unsigned short Xs[64*72];
  __shared__ __align__(16) unsigned short F1[64*136];
  __shared__ float b1s[128], b2s[64], l2w[64], l2b[64], bcs[40];
  unsigned short* hsH = F1;              // 16x72, aliases dead F1
  unsigned short* hsL = F1 + 16*72;      // 16x72
  const int tid = threadIdx.x;
  if (tid < 128) b1s[tid] = b1[tid];
  if (tid < 64){ b2s[tid]=b2[tid]; l2w[tid]=ln2w[tid]; l2b[tid]=ln2b[tid]; }
  if (tid < 40)  bcs[tid] = bc[tid];
  const int w = tid >> 6, lane = tid & 63, quad = lane >> 4, c = lane & 15;
  const int rw = w*16;
  const unsigned short* W1g = wp + WP_W1;
  const unsigned short* W2g = wp + WP_W2;
  const unsigned short* Wcg = wp + WP_WC;
  for (int g = blockIdx.x; g < NG; g += gridDim.x){
    __syncthreads();
    for (int idx = tid; idx < 512; idx += 256){
      int r = idx >> 3, ch = idx & 7;
      int t = r & 3, n = g*16 + (r >> 2);
      *(uint4*)&Xs[r*72 + ch*8] = *(const uint4*)(tokB + ((size_t)t*NN + n)*64 + ch*8);
    }
    __syncthreads();
    bf16x8 a0 = *(const bf16x8*)&Xs[(rw+c)*72 + quad*8];
    bf16x8 a1 = *(const bf16x8*)&Xs[(rw+c)*72 + 32 + quad*8];
    // ff1 + exact gelu (branch-free poly) -> F1 (A-layout bf16, wave-private rows)
    #pragma unroll
    for (int nt = 0; nt < 8; ++nt){
      f32x4 acc = {0,0,0,0};
      bf16x8 b0 = *(const bf16x8*)&W1g[(nt*16+c)*72 + quad*8];
      bf16x8 b1v = *(const bf16x8*)&W1g[(nt*16+c)*72 + 32 + quad*8];
      acc = __builtin_amdgcn_mfma_f32_16x16x32_bf16(a0, b0, acc, 0,0,0);
      acc = __builtin_amdgcn_mfma_f32_16x16x32_bf16(a1, b1v, acc, 0,0,0);
      float bb = b1s[nt*16 + c];
      #pragma unroll
      for (int rg = 0; rg < 4; ++rg){
        float v = acc[rg] + bb;
        F1[(rw + quad*4 + rg)*136 + nt*16 + c] = f2us(gelu_f(v));
      }
    }
    // ff2 (same-wave LDS in-order)
    bf16x8 fa[4];
    #pragma unroll
    for (int ks = 0; ks < 4; ++ks)
      fa[ks] = *(const bf16x8*)&F1[(rw+c)*136 + ks*32 + quad*8];
    __syncthreads();   // all fa in regs before hs writes overwrite F1 region
    f32x4 ov[4];
    #pragma unroll
    for (int nt = 0; nt < 4; ++nt){
      f32x4 acc = {0,0,0,0};
      #pragma unroll
      for (int ks = 0; ks < 4; ++ks){
        bf16x8 b = *(const bf16x8*)&W2g[(nt*16+c)*136 + ks*32 + quad*8];
        acc = __builtin_amdgcn_mfma_f32_16x16x32_bf16(fa[ks], b, acc, 0,0,0);
      }
      ov[nt] = acc;
    }
    float r4[4][4];
    #pragma unroll
    for (int nt = 0; nt < 4; ++nt){
      int col = nt*16 + c;
      float bb = b2s[col];
      #pragma unroll
      for (int rg = 0; rg < 4; ++rg){
        float seqv = us2f(Xs[(rw + quad*4 + rg)*72 + col]);
        r4[nt][rg] = ov[nt][rg] + bb + seqv;
      }
    }
    float hval[4] = {0.f, 0.f, 0.f, 0.f};
    #pragma unroll
    for (int rg = 0; rg < 4; ++rg){
      float sm = r4[0][rg]+r4[1][rg]+r4[2][rg]+r4[3][rg];
      sm += __shfl_xor(sm,1); sm += __shfl_xor(sm,2);
      sm += __shfl_xor(sm,4); sm += __shfl_xor(sm,8);
      float mean = sm * (1.f/64.f);
      float d0=r4[0][rg]-mean, d1=r4[1][rg]-mean, d2=r4[2][rg]-mean, d3=r4[3][rg]-mean;
      float vs = d0*d0+d1*d1+d2*d2+d3*d3;
      vs += __shfl_xor(vs,1); vs += __shfl_xor(vs,2);
      vs += __shfl_xor(vs,4); vs += __shfl_xor(vs,8);
      float rinv = rsqrtf(vs*(1.f/64.f) + 1e-5f);
      #pragma unroll
      for (int nt = 0; nt < 4; ++nt){
        int col = nt*16 + c;
        hval[nt] += (r4[nt][rg] - mean) * rinv * l2w[col] + l2b[col];
      }
    }
    // h (16x64) as bf16 hi+lo planes for exact-ish MFMA classifier
    #pragma unroll
    for (int nt = 0; nt < 4; ++nt){
      float hv = hval[nt] * 0.25f;
      unsigned short hh = f2us(hv);
      float lo = hv - us2f(hh);
      hsH[(w*4 + quad)*72 + nt*16 + c] = hh;
      hsL[(w*4 + quad)*72 + nt*16 + c] = f2us(lo);
    }
    __syncthreads();
    // classifier: out(16x40) = h @ Wc^T via MFMA, waves 0-2 each own a 16-col tile
    if (w < 3){
      bf16x8 hA0 = *(const bf16x8*)&hsH[c*72 + quad*8];
      bf16x8 hA1 = *(const bf16x8*)&hsH[c*72 + 32 + quad*8];
      bf16x8 lA0 = *(const bf16x8*)&hsL[c*72 + quad*8];
      bf16x8 lA1 = *(const bf16x8*)&hsL[c*72 + 32 + quad*8];
      bf16x8 wB0 = *(const bf16x8*)&Wcg[(w*16 + c)*72 + quad*8];
      bf16x8 wB1 = *(const bf16x8*)&Wcg[(w*16 + c)*72 + 32 + quad*8];
      f32x4 acc = {0,0,0,0};
      acc = __builtin_amdgcn_mfma_f32_16x16x32_bf16(hA0, wB0, acc, 0,0,0);
      acc = __builtin_amdgcn_mfma_f32_16x16x32_bf16(hA1, wB1, acc, 0,0,0);
      acc = __builtin_amdgcn_mfma_f32_16x16x32_bf16(lA0, wB0, acc, 0,0,0);
      acc = __builtin_amdgcn_mfma_f32_16x16x32_bf16(lA1, wB1, acc, 0,0,0);
      int o = w*16 + c;
      if (o < OUTC){
        float bb = bcs[o];
        #pragma unroll
        for (int rg = 0; rg < 4; ++rg)
          out[(size_t)(g*16 + quad*4 + rg)*OUTC + o] = acc[rg] + bb;
      }
    }
  }
}

extern "C" void kernel_launch(void* const* d_in, const int* in_sizes, int n_in,
                              void* d_out, int out_size, void* d_ws, size_t ws_size,
                              hipStream_t stream) {
  const float* x    = (const float*)d_in[0];
  const int*   ei   = (const int*  )d_in[1];
  const float* Win  = (const float*)d_in[2];
  const float* bin  = (const float*)d_in[3];
  const float* sgW  = (const float*)d_in[4];
  const float* sgb  = (const float*)d_in[5];
  const float* Wqkv = (const float*)d_in[6];
  const float* bqkv = (const float*)d_in[7];
  const float* Wo   = (const float*)d_in[8];
  const float* bo   = (const float*)d_in[9];
  const float* W1   = (const float*)d_in[10];
  const float* b1   = (const float*)d_in[11];
  const float* W2   = (const float*)d_in[12];
  const float* b2   = (const float*)d_in[13];
  const float* ln1w = (const float*)d_in[14];
  const float* ln1b = (const float*)d_in[15];
  const float* ln2w = (const float*)d_in[16];
  const float* ln2b = (const float*)d_in[17];
  const float* Wc   = (const float*)d_in[18];
  const float* bc   = (const float*)d_in[19];

  char* ws = (char*)d_ws;
  float*          dinv    = (float*)(ws);                     // 400,000 B
  int*            cnt     = (int*  )(ws + 400128);            // 400,000 B (degree)
  unsigned short* wp      = (unsigned short*)(ws + 800256);   // 141,056 B (ends 941,312)
  int*            binFill = (int*)(ws + 941312);              // 1,564 B (own slot, no alias)
  unsigned short* tokB    = (unsigned short*)(ws + 943104);   // 4*N*64*2 = 51,200,000 B
  unsigned short* pb0     = (unsigned short*)(ws + 52143104); // 12,800,000 B
  unsigned short* pb1     = (unsigned short*)(ws + 64943104); // 12,800,000 B
  // Aliases (lifetimes disjoint):
  //  - binned (9.6 MB, packed int): tok slot 1; dead after k_buckh0 (bucket),
  //    slot1 first written by tok1 in k_tokgather (later)
  //  - srcb (25.6 MB): tok slots 2+3; dead after gather3, written by k_tok23 after
  int* binned = (int*)(tokB + (size_t)1*NN*64);
  int* srcb   = (int*)(tokB + (size_t)2*NN*64);

  // prep: {zero binFill || weight prepack}
  k_prep0<<<130, 256, 0, stream>>>(Win, sgW, Wqkv, Wo, W1, W2, Wc, wp, binFill);
  // CSR pass 1
  k_bin<<<512, 256, 0, stream>>>(ei, binFill, binned);
  // {CSR pass 2 || h0}:  tok0 -> slot0, p0 -> pb1
  k_buckh0<<<NBIN + GB, 256, 0, stream>>>(binFill, binned, srcb, cnt, dinv,
                                          x, wp, bin, tokB, pb1);
  // hop 1: p1 = S p0
  k_gather<<<GG, 256, 0, stream>>>(cnt, srcb, dinv, pb1, pb0);
  // {tok1 (from p1) || hop 2: p2 = S p1}
  k_tokgather<<<GB + GG, 256, 0, stream>>>(pb0, wp + WP_SG, sgb, tokB + (size_t)1*NN*64,
                                           cnt, srcb, dinv, pb0, pb1);
  // hop 3: p3 = S p2   (last srcb consumer)
  k_gather<<<GG, 256, 0, stream>>>(cnt, srcb, dinv, pb1, pb0);
  // {tok2 (from p2=pb1) || tok3 (from p3=pb0)}
  k_tok23<<<2*GB, 256, 0, stream>>>(pb1, wp + WP_SG + 4608, sgb + 64,  tokB + (size_t)2*NN*64,
                                    pb0, wp + WP_SG + 9216, sgb + 128, tokB + (size_t)3*NN*64);

  k_attn<<<2084, 256, 0, stream>>>(tokB, wp, bqkv, bo, ln1w, ln1b);
  k_ffn <<<2084, 256, 0, stream>>>(tokB, wp, b1, b2, ln2w, ln2b, bc, (float*)d_out);
}

// Round 17
// 595.993 us; speedup vs baseline: 1.0224x; 1.0224x over previous
//
#include <hip/hip_runtime.h>
#include <hip/hip_bf16.h>
#include <math.h>

#define NN 100000
#define EE 1600000
#define OUTC 40
#define NB 391            // (NN+255)/256
#define NG 6250           // NN/16 groups for attn/ffn
#define CAP 64            // bucket capacity per node (deg ~ Poisson(16))
#define NBIN 391          // bins of 256 nodes
#define BCAP 6144         // edges per bin capacity (E[X]=4194, sigma=65)
#define GB 1563           // (NN+63)/64 token/h0 blocks
#define GG 25000          // gather blocks (wave per node)

// prepacked-weight offsets (in shorts), padded to LDS strides
#define WP_WIN 0          // 64 x 264   (Win 64x256)
#define WP_SG  16896      // 3 x 64 x 72 (sgW 3x64x64)
#define WP_QKV 30720      // 192 x 72
#define WP_WO  44544      // 64 x 72
#define WP_W1  49152      // 128 x 72
#define WP_W2  58368      // 64 x 136  (W2 64x128)
#define WP_WC  67072      // 48 x 72  (rows 40-47 zeroed)
#define WP_TOT 70528

typedef __hip_bfloat16 bf16;
typedef __attribute__((ext_vector_type(8))) short bf16x8;
typedef __attribute__((ext_vector_type(4))) float f32x4;

__device__ __forceinline__ unsigned short f2us(float f){
  bf16 b = __float2bfloat16(f);
  unsigned short u; __builtin_memcpy(&u, &b, 2); return u;
}
__device__ __forceinline__ float us2f(unsigned short u){
  union{unsigned x; float f;} c; c.x = ((unsigned)u)<<16; return c.f;
}
__device__ __forceinline__ float lo_f(unsigned u){ union{unsigned x;float f;}c; c.x = u<<16; return c.f; }
__device__ __forceinline__ float hi_f(unsigned u){ union{unsigned x;float f;}c; c.x = u & 0xffff0000u; return c.f; }

// branch-free exact-erf gelu (A&S 7.1.26, |erf err| <= 1.5e-7)
__device__ __forceinline__ float gelu_f(float v){
  float ax = fabsf(v);
  float t  = __builtin_amdgcn_rcpf(fmaf(0.3275911f, ax, 1.0f));
  float p  = fmaf(t, 1.061405429f, -1.453152027f);
  p = fmaf(t, p, 1.421413741f);
  p = fmaf(t, p, -0.284496736f);
  p = fmaf(t, p, 0.254829592f);
  p = p * t;
  float ex = __expf(-ax*ax);
  float er = fmaf(-p, ex, 1.0f);       // erf(|v|)
  er = copysignf(er, v);
  return 0.5f * v * (1.0f + er);
}

// ---------------- prep: {zero binFill || weight prepack} ----------------
__global__ void k_prep0(const float* __restrict__ Win, const float* __restrict__ sgW,
                        const float* __restrict__ Wqkv, const float* __restrict__ Wo,
                        const float* __restrict__ W1, const float* __restrict__ W2,
                        const float* __restrict__ Wc, unsigned short* __restrict__ wp,
                        int* __restrict__ binFill){
  if (blockIdx.x < 2){
    int i = blockIdx.x*256 + threadIdx.x;
    if (i < NBIN) binFill[i] = 0;
    return;
  }
  const int bid = blockIdx.x - 2;
  for (int idx = bid*256 + threadIdx.x; idx < WP_TOT; idx += 128*256){
    float v; int o;
    if (idx < WP_SG){ o = idx; int r=o/264, c=o-r*264; v = (c<256)? Win[r*256+c] : 0.f; }
    else if (idx < WP_QKV){ o = idx-WP_SG; int h=o/4608, rem=o-h*4608, r=rem/72, c=rem-r*72;
      v=(c<64)? sgW[h*4096+r*64+c] : 0.f; }
    else if (idx < WP_WO){ o = idx-WP_QKV; int r=o/72, c=o-r*72; v=(c<64)? Wqkv[r*64+c]:0.f; }
    else if (idx < WP_W1){ o = idx-WP_WO; int r=o/72, c=o-r*72; v=(c<64)? Wo[r*64+c]:0.f; }
    else if (idx < WP_W2){ o = idx-WP_W1; int r=o/72, c=o-r*72; v=(c<64)? W1[r*64+c]:0.f; }
    else if (idx < WP_WC){ o = idx-WP_W2; int r=o/136, c=o-r*136; v=(c<128)? W2[r*128+c]:0.f; }
    else { o = idx-WP_WC; int r=o/72, c=o-r*72; v=(r<OUTC && c<64)? Wc[r*64+c]:0.f; }
    wp[idx] = f2us(v);
  }
}

// ---------------- CSR pass 1: bin edges (packed int: src | dl<<24) ----------------
__global__ void __launch_bounds__(256) k_bin(const int* __restrict__ ei,
    int* __restrict__ binFill, int* __restrict__ binned){
  __shared__ int hist[NBIN], sbase[NBIN], loc[NBIN];
  const int tid = threadIdx.x;
  const int CH = (EE + gridDim.x - 1) / gridDim.x;
  const int e0 = blockIdx.x * CH;
  const int e1 = min(e0 + CH, EE);
  for (int i = tid; i < NBIN; i += 256){ hist[i] = 0; loc[i] = 0; }
  __syncthreads();
  for (int e = e0 + tid; e < e1; e += 256)
    atomicAdd(&hist[ei[EE + e] >> 8], 1);
  __syncthreads();
  for (int i = tid; i < NBIN; i += 256)
    sbase[i] = atomicAdd(&binFill[i], hist[i]);
  __syncthreads();
  for (int e = e0 + tid; e < e1; e += 256){
    int d = ei[EE + e];
    int s = ei[e];
    int b = d >> 8;
    int p = sbase[b] + atomicAdd(&loc[b], 1);
    if (p < BCAP) binned[(size_t)b*BCAP + p] = s | ((d & 255) << 24);
  }
}

// ---------------- bucket body (CSR pass 2) ----------------
__device__ __forceinline__ void bucket_body(const int* __restrict__ binFill,
    const int* __restrict__ binned, int* __restrict__ srcb,
    int* __restrict__ cnt, float* __restrict__ dinv, int* lcnt, int b){
  const int tid = threadIdx.x;
  lcnt[tid] = 0;
  __syncthreads();
  int m = binFill[b]; if (m > BCAP) m = BCAP;
  const int* seg = binned + (size_t)b*BCAP;
  for (int e = tid; e < m; e += 256){
    int v = seg[e];
    int dl = ((unsigned)v) >> 24;
    int s = v & 0xFFFFFF;
    int p = atomicAdd(&lcnt[dl], 1);
    if (p < CAP) srcb[((size_t)(b << 8) + dl)*CAP + p] = s;
  }
  __syncthreads();
  int d = (b << 8) + tid;
  if (d < NN){
    int c = lcnt[tid];
    dinv[d] = rsqrtf((float)c + 1.0f);
    cnt[d] = min(c, CAP);
  }
}

// ---------------- h0 body: relu(x @ Win^T + b) -> tok0 and p0 ----------------
// Win B-fragments read directly from the global wp image; only X staged in LDS.
__device__ __forceinline__ void h0_body(const float* __restrict__ x,
    const unsigned short* __restrict__ wp, const float* __restrict__ bin,
    unsigned short* __restrict__ tok0, unsigned short* __restrict__ p0,
    unsigned short* Xs, float* bs, int bid){
  const int tid = threadIdx.x;
  const unsigned short* Wg = wp + WP_WIN;
  const int n0 = bid * 64;
  for (int idx = tid; idx < 4096; idx += 256){       // X tile: 64x256, fp32->bf16
    int r = idx >> 6, c0 = (idx & 63) * 4;
    int n = n0 + r; if (n >= NN) n = NN-1;
    float4 v = *(const float4*)(x + (size_t)n*256 + c0);
    unsigned short* d = &Xs[r*264 + c0];
    d[0]=f2us(v.x); d[1]=f2us(v.y); d[2]=f2us(v.z); d[3]=f2us(v.w);
  }
  if (tid < 64) bs[tid] = bin[tid];
  __syncthreads();
  const int w = tid >> 6, lane = tid & 63, quad = lane >> 4, c = lane & 15;
  f32x4 acc[4] = {{0,0,0,0},{0,0,0,0},{0,0,0,0},{0,0,0,0}};
  #pragma unroll
  for (int ks = 0; ks < 8; ++ks){
    int k0 = ks*32 + quad*8;
    bf16x8 a = *(const bf16x8*)&Xs[(w*16 + c)*264 + k0];
    #pragma unroll
    for (int nt = 0; nt < 4; ++nt){
      bf16x8 b = *(const bf16x8*)&Wg[(nt*16 + c)*264 + k0];
      acc[nt] = __builtin_amdgcn_mfma_f32_16x16x32_bf16(a, b, acc[nt], 0,0,0);
    }
  }
  __syncthreads();
  #pragma unroll
  for (int nt = 0; nt < 4; ++nt){
    int col = nt*16 + c;
    float bb = bs[col];
    #pragma unroll
    for (int rg = 0; rg < 4; ++rg){
      int rloc = w*16 + quad*4 + rg;
      Xs[rloc*72 + col] = f2us(fmaxf(acc[nt][rg] + bb, 0.f));
    }
  }
  __syncthreads();
  for (int idx = tid; idx < 512; idx += 256){
    int r = idx >> 3, ch = idx & 7;
    int n = n0 + r;
    if (n < NN){
      uint4 v = *(const uint4*)&Xs[r*72 + ch*8];
      *(uint4*)(tok0 + (size_t)n*64 + ch*8) = v;
      *(uint4*)(p0   + (size_t)n*64 + ch*8) = v;
    }
  }
}

// ---------------- merged: {bucket || h0} ----------------
__global__ void __launch_bounds__(256) k_buckh0(const int* __restrict__ binFill,
    const int* __restrict__ binned, int* __restrict__ srcb,
    int* __restrict__ cnt, float* __restrict__ dinv,
    const float* __restrict__ x, const unsigned short* __restrict__ wp,
    const float* __restrict__ bin, unsigned short* __restrict__ tok0,
    unsigned short* __restrict__ p0){
  __shared__ __align__(16) unsigned short Xs[64*264];
  __shared__ float bs[64];
  __shared__ int lcnt[256];
  if (blockIdx.x < NBIN)
    bucket_body(binFill, binned, srcb, cnt, dinv, lcnt, blockIdx.x);
  else
    h0_body(x, wp, bin, tok0, p0, Xs, bs, blockIdx.x - NBIN);
}

// ---------------- gather body: cur = S @ prev (full-MLP, 8 lanes/edge) ----------
#define GACC(r, wt) \
  a0 += lo_f((r).x)*(wt); a1 += hi_f((r).x)*(wt); \
  a2 += lo_f((r).y)*(wt); a3 += hi_f((r).y)*(wt); \
  a4 += lo_f((r).z)*(wt); a5 += hi_f((r).z)*(wt); \
  a6 += lo_f((r).w)*(wt); a7 += hi_f((r).w)*(wt);

__device__ __forceinline__ void gather_body(const int* __restrict__ cnt,
    const int* __restrict__ srcb, const float* __restrict__ dinv,
    const unsigned short* __restrict__ prev, unsigned short* __restrict__ cur,
    int bid){
  int wid = (bid << 2) + (threadIdx.x >> 6);
  if (wid >= NN) return;
  const int lane = threadIdx.x & 63;
  const int grp = lane >> 3, cl = lane & 7;     // 8 groups x 8 lanes
  const int n = wid;
  const int deg = cnt[n];                        // wave-uniform
  const int* bk = srcb + (size_t)n*CAP;
  const float dn = dinv[n];
  uint4 sr = *(const uint4*)(prev + ((size_t)n << 6) + (cl << 3));
  int sv[8];
  #pragma unroll
  for (int j = 0; j < 8; ++j){
    sv[j] = n;
    if (j*8 < deg){
      int idx = j*8 + grp;
      if (idx < deg) sv[j] = bk[idx];
    }
  }
  float wv[8];
  #pragma unroll
  for (int j = 0; j < 8; ++j){
    wv[j] = 0.f;
    if (j*8 < deg){
      int idx = j*8 + grp;
      if (idx < deg) wv[j] = dinv[sv[j]] * dn;
    }
  }
  uint4 rr[8];
  #pragma unroll
  for (int j = 0; j < 8; ++j){
    if (j*8 < deg)
      rr[j] = *(const uint4*)(prev + ((size_t)sv[j] << 6) + (cl << 3));
  }
  float a0=0,a1=0,a2=0,a3=0,a4=0,a5=0,a6=0,a7=0;
  #pragma unroll
  for (int j = 0; j < 8; ++j){
    if (j*8 < deg){ GACC(rr[j], wv[j]); }
  }
  a0 += __shfl_xor(a0,8); a0 += __shfl_xor(a0,16); a0 += __shfl_xor(a0,32);
  a1 += __shfl_xor(a1,8); a1 += __shfl_xor(a1,16); a1 += __shfl_xor(a1,32);
  a2 += __shfl_xor(a2,8); a2 += __shfl_xor(a2,16); a2 += __shfl_xor(a2,32);
  a3 += __shfl_xor(a3,8); a3 += __shfl_xor(a3,16); a3 += __shfl_xor(a3,32);
  a4 += __shfl_xor(a4,8); a4 += __shfl_xor(a4,16); a4 += __shfl_xor(a4,32);
  a5 += __shfl_xor(a5,8); a5 += __shfl_xor(a5,16); a5 += __shfl_xor(a5,32);
  a6 += __shfl_xor(a6,8); a6 += __shfl_xor(a6,16); a6 += __shfl_xor(a6,32);
  a7 += __shfl_xor(a7,8); a7 += __shfl_xor(a7,16); a7 += __shfl_xor(a7,32);
  if (lane < 8){
    float d2 = dn*dn;
    GACC(sr, d2);
    uint4 pk;
    pk.x = (unsigned)f2us(a0) | ((unsigned)f2us(a1) << 16);
    pk.y = (unsigned)f2us(a2) | ((unsigned)f2us(a3) << 16);
    pk.z = (unsigned)f2us(a4) | ((unsigned)f2us(a5) << 16);
    pk.w = (unsigned)f2us(a6) | ((unsigned)f2us(a7) << 16);
    *(uint4*)(cur + ((size_t)n << 6) + (cl << 3)) = pk;
  }
}

__global__ void __launch_bounds__(256) k_gather(const int* __restrict__ cnt,
    const int* __restrict__ srcb, const float* __restrict__ dinv,
    const unsigned short* __restrict__ prev, unsigned short* __restrict__ cur){
  gather_body(cnt, srcb, dinv, prev, cur, blockIdx.x);
}

// ---------------- token body: relu(cur @ sgW^T + sgb) -> tok ----------------
__device__ __forceinline__ void tok_body(const unsigned short* __restrict__ cur,
    const unsigned short* __restrict__ wsg, const float* __restrict__ sgb,
    unsigned short* __restrict__ tok,
    unsigned short* Xs, unsigned short* Ws, float* bs, int bid){
  const int tid = threadIdx.x;
  {
    const uint4* src = (const uint4*)wsg;
    for (int idx = tid; idx < 576; idx += 256) ((uint4*)Ws)[idx] = src[idx];
  }
  if (tid < 64) bs[tid] = sgb[tid];
  const int n0 = bid*64;
  for (int idx = tid; idx < 512; idx += 256){
    int r = idx >> 3, ch = idx & 7;
    int n = n0 + r; if (n >= NN) n = NN-1;
    *(uint4*)&Xs[r*72 + ch*8] = *(const uint4*)(cur + (size_t)n*64 + ch*8);
  }
  __syncthreads();
  const int w = tid >> 6, lane = tid & 63, quad = lane >> 4, c = lane & 15;
  f32x4 acc[4] = {{0,0,0,0},{0,0,0,0},{0,0,0,0},{0,0,0,0}};
  #pragma unroll
  for (int ks = 0; ks < 2; ++ks){
    int k0 = ks*32 + quad*8;
    bf16x8 a = *(const bf16x8*)&Xs[(w*16 + c)*72 + k0];
    #pragma unroll
    for (int nt = 0; nt < 4; ++nt){
      bf16x8 b = *(const bf16x8*)&Ws[(nt*16 + c)*72 + k0];
      acc[nt] = __builtin_amdgcn_mfma_f32_16x16x32_bf16(a, b, acc[nt], 0,0,0);
    }
  }
  __syncthreads();
  #pragma unroll
  for (int nt = 0; nt < 4; ++nt){
    int col = nt*16 + c;
    float bb = bs[col];
    #pragma unroll
    for (int rg = 0; rg < 4; ++rg){
      int rloc = w*16 + quad*4 + rg;
      Xs[rloc*72 + col] = f2us(fmaxf(acc[nt][rg] + bb, 0.f));
    }
  }
  __syncthreads();
  for (int idx = tid; idx < 512; idx += 256){
    int r = idx >> 3, ch = idx & 7;
    int n = n0 + r;
    if (n < NN)
      *(uint4*)(tok + (size_t)n*64 + ch*8) = *(const uint4*)&Xs[r*72 + ch*8];
  }
}

// ---------------- merged: {token || gather} ----------------
__global__ void __launch_bounds__(256) k_tokgather(
    const unsigned short* __restrict__ tcur, const unsigned short* __restrict__ wsg,
    const float* __restrict__ sgb, unsigned short* __restrict__ tok,
    const int* __restrict__ cnt, const int* __restrict__ srcb,
    const float* __restrict__ dinv, const unsigned short* __restrict__ prev,
    unsigned short* __restrict__ cur){
  __shared__ __align__(16) unsigned short Xs[64*72];
  __shared__ __align__(16) unsigned short Ws[64*72];
  __shared__ float bs[64];
  if (blockIdx.x < GB)
    tok_body(tcur, wsg, sgb, tok, Xs, Ws, bs, blockIdx.x);
  else
    gather_body(cnt, srcb, dinv, prev, cur, blockIdx.x - GB);
}

// ---------------- merged: {token2 || token3} ----------------
__global__ void __launch_bounds__(256) k_tok23(
    const unsigned short* __restrict__ curA, const unsigned short* __restrict__ wsgA,
    const float* __restrict__ sgbA, unsigned short* __restrict__ tokA,
    const unsigned short* __restrict__ curB, const unsigned short* __restrict__ wsgB,
    const float* __restrict__ sgbB, unsigned short* __restrict__ tokOutB){
  __shared__ __align__(16) unsigned short Xs[64*72];
  __shared__ __align__(16) unsigned short Ws[64*72];
  __shared__ float bs[64];
  if (blockIdx.x < GB)
    tok_body(curA, wsgA, sgbA, tokA, Xs, Ws, bs, blockIdx.x);
  else
    tok_body(curB, wsgB, sgbB, tokOutB, Xs, Ws, bs, blockIdx.x - GB);
}

// ---------------- attention + LN1 (persistent) ----------------
// All 12 QKV tiles up-front (max MFMA ILP); Xs read-only per iteration;
// P@V + LN1 output into Ps. Grid 2048 = 2 clean scheduling rounds at
// 4 blocks/CU (2084 measured worse: 2.03-round dispatch tail).
__global__ void __launch_bounds__(256) k_attn(unsigned short* __restrict__ tokB,
    const unsigned short* __restrict__ wp, const float* __restrict__ bqkv,
    const float* __restrict__ bo, const float* __restrict__ ln1w,
    const float* __restrict__ ln1b){
  __shared__ __align__(16) unsigned short Xs[64*72];
  __shared__ __align__(16) unsigned short Ps[64*72];
  __shared__ float bq[192], bos[64], l1w[64], l1b[64];
  const int tid = threadIdx.x;
  if (tid < 192) bq[tid] = bqkv[tid];
  if (tid < 64){ bos[tid]=bo[tid]; l1w[tid]=ln1w[tid]; l1b[tid]=ln1b[tid]; }
  const int w = tid >> 6, lane = tid & 63, quad = lane >> 4, c = lane & 15;
  const int rw = w*16;
  const unsigned short* Wq  = wp + WP_QKV;
  const unsigned short* Wos = wp + WP_WO;
  for (int g = blockIdx.x; g < NG; g += gridDim.x){
    __syncthreads();        // protect Xs/Ps from previous iteration readers
    for (int idx = tid; idx < 512; idx += 256){     // stage 64 rows of bf16 tokens
      int r = idx >> 3, ch = idx & 7;
      int t = r & 3, n = g*16 + (r >> 2);           // row = node_local*4 + t
      *(uint4*)&Xs[r*72 + ch*8] = *(const uint4*)(tokB + ((size_t)t*NN + n)*64 + ch*8);
    }
    __syncthreads();
    bf16x8 a0 = *(const bf16x8*)&Xs[(rw+c)*72 + quad*8];
    bf16x8 a1 = *(const bf16x8*)&Xs[(rw+c)*72 + 32 + quad*8];
    f32x4 qk[12];   // 0-3: q tiles, 4-7: k tiles, 8-11: v tiles
    #pragma unroll
    for (int nt = 0; nt < 12; ++nt){
      f32x4 acc = {0,0,0,0};
      bf16x8 b0 = *(const bf16x8*)&Wq[(nt*16+c)*72 + quad*8];
      bf16x8 b1 = *(const bf16x8*)&Wq[(nt*16+c)*72 + 32 + quad*8];
      acc = __builtin_amdgcn_mfma_f32_16x16x32_bf16(a0, b0, acc, 0,0,0);
      acc = __builtin_amdgcn_mfma_f32_16x16x32_bf16(a1, b1, acc, 0,0,0);
      float bb = bq[nt*16 + c];
      acc[0]+=bb; acc[1]+=bb; acc[2]+=bb; acc[3]+=bb;
      qk[nt] = acc;
    }
    float sc[4][4];
    #pragma unroll
    for (int s = 0; s < 4; ++s){
      #pragma unroll
      for (int t = 0; t < 4; ++t){
        float p = qk[0][s]*qk[4][t] + qk[1][s]*qk[5][t]
                + qk[2][s]*qk[6][t] + qk[3][s]*qk[7][t];
        p += __shfl_xor(p, 1); p += __shfl_xor(p, 2);
        p += __shfl_xor(p, 4); p += __shfl_xor(p, 8);
        sc[s][t] = p * 0.125f;
      }
    }
    float pm[4][4];
    #pragma unroll
    for (int s = 0; s < 4; ++s){
      float m = fmaxf(fmaxf(sc[s][0],sc[s][1]), fmaxf(sc[s][2],sc[s][3]));
      float e0=__expf(sc[s][0]-m), e1=__expf(sc[s][1]-m);
      float e2=__expf(sc[s][2]-m), e3=__expf(sc[s][3]-m);
      float inv = 1.f/(e0+e1+e2+e3);
      pm[s][0]=e0*inv; pm[s][1]=e1*inv; pm[s][2]=e2*inv; pm[s][3]=e3*inv;
    }
    // P@V -> Ps in A-layout (wave-private rows; Xs untouched)
    #pragma unroll
    for (int tile = 0; tile < 4; ++tile){
      #pragma unroll
      for (int s = 0; s < 4; ++s){
        float av = pm[s][0]*qk[8+tile][0] + pm[s][1]*qk[8+tile][1]
                 + pm[s][2]*qk[8+tile][2] + pm[s][3]*qk[8+tile][3];
        Ps[(rw + quad*4 + s)*72 + tile*16 + c] = f2us(av);
      }
    }
    bf16x8 p0 = *(const bf16x8*)&Ps[(rw+c)*72 + quad*8];
    bf16x8 p1 = *(const bf16x8*)&Ps[(rw+c)*72 + 32 + quad*8];
    f32x4 ov[4];
    #pragma unroll
    for (int nt = 0; nt < 4; ++nt){
      f32x4 acc = {0,0,0,0};
      bf16x8 b0 = *(const bf16x8*)&Wos[(nt*16+c)*72 + quad*8];
      bf16x8 b1 = *(const bf16x8*)&Wos[(nt*16+c)*72 + 32 + quad*8];
      acc = __builtin_amdgcn_mfma_f32_16x16x32_bf16(p0, b0, acc, 0,0,0);
      acc = __builtin_amdgcn_mfma_f32_16x16x32_bf16(p1, b1, acc, 0,0,0);
      ov[nt] = acc;
    }
    float r4[4][4];
    #pragma unroll
    for (int nt = 0; nt < 4; ++nt){
      int col = nt*16 + c;
      float bb = bos[col];
      #pragma unroll
      for (int rg = 0; rg < 4; ++rg){
        float seqv = us2f(Xs[(rw + quad*4 + rg)*72 + col]);   // residual from intact Xs
        r4[nt][rg] = ov[nt][rg] + bb + seqv;
      }
    }
    #pragma unroll
    for (int rg = 0; rg < 4; ++rg){
      float sm = r4[0][rg]+r4[1][rg]+r4[2][rg]+r4[3][rg];
      sm += __shfl_xor(sm,1); sm += __shfl_xor(sm,2);
      sm += __shfl_xor(sm,4); sm += __shfl_xor(sm,8);
      float mean = sm * (1.f/64.f);
      float d0=r4[0][rg]-mean, d1=r4[1][rg]-mean, d2=r4[2][rg]-mean, d3=r4[3][rg]-mean;
      float vs = d0*d0+d1*d1+d2*d2+d3*d3;
      vs += __shfl_xor(vs,1); vs += __shfl_xor(vs,2);
      vs += __shfl_xor(vs,4); vs += __shfl_xor(vs,8);
      float rinv = rsqrtf(vs*(1.f/64.f) + 1e-5f);
      int row = rw + quad*4 + rg;
      #pragma unroll
      for (int nt = 0; nt < 4; ++nt){
        int col = nt*16 + c;
        Ps[row*72 + col] = f2us((r4[nt][rg] - mean) * rinv * l1w[col] + l1b[col]);
      }
    }
    __syncthreads();
    for (int idx = tid; idx < 512; idx += 256){     // coalesced copy-out from Ps
      int r = idx >> 3, ch = idx & 7;
      int t = r & 3, n = g*16 + (r >> 2);
      *(uint4*)(tokB + ((size_t)t*NN + n)*64 + ch*8) = *(const uint4*)&Ps[r*72 + ch*8];
    }
  }
}

// ---------------- FFN + LN2 + mean + classifier (persistent) ----------------
__global__ void __launch_bounds__(256) k_ffn(const unsigned short* __restrict__ tokB,
    const unsigned short* __restrict__ wp,
    const float* __restrict__ b1, const float* __restrict__ b2,
    const float* __restrict__ ln2w, const float* __restrict__ ln2b,
    const float* __restrict__ bc, float* __restrict__ out){
  __shared__ __align__(16) unsigned short Xs[64*72];
  __shared__ __align__(16) unsigned short F1[64*136];
  __shared__ float b1s[128], b2s[64], l2w[64], l2b[64], bcs[40];
  unsigned short* hsH = F1;              // 16x72, aliases dead F1
  unsigned short* hsL = F1 + 16*72;      // 16x72
  const int tid = threadIdx.x;
  if (tid < 128) b1s[tid] = b1[tid];
  if (tid < 64){ b2s[tid]=b2[tid]; l2w[tid]=ln2w[tid]; l2b[tid]=ln2b[tid]; }
  if (tid < 40)  bcs[tid] = bc[tid];
  const int w = tid >> 6, lane = tid & 63, quad = lane >> 4, c = lane & 15;
  const int rw = w*16;
  const unsigned short* W1g = wp + WP_W1;
  const unsigned short* W2g = wp + WP_W2;
  const unsigned short* Wcg = wp + WP_WC;
  for (int g = blockIdx.x; g < NG; g += gridDim.x){
    __syncthreads();
    for (int idx = tid; idx < 512; idx += 256){
      int r = idx >> 3, ch = idx & 7;
      int t = r & 3, n = g*16 + (r >> 2);
      *(uint4*)&Xs[r*72 + ch*8] = *(const uint4*)(tokB + ((size_t)t*NN + n)*64 + ch*8);
    }
    __syncthreads();
    bf16x8 a0 = *(const bf16x8*)&Xs[(rw+c)*72 + quad*8];
    bf16x8 a1 = *(const bf16x8*)&Xs[(rw+c)*72 + 32 + quad*8];
    // ff1 + exact gelu (branch-free poly) -> F1 (A-layout bf16, wave-private rows)
    #pragma unroll
    for (int nt = 0; nt < 8; ++nt){
      f32x4 acc = {0,0,0,0};
      bf16x8 b0 = *(const bf16x8*)&W1g[(nt*16+c)*72 + quad*8];
      bf16x8 b1v = *(const bf16x8*)&W1g[(nt*16+c)*72 + 32 + quad*8];
      acc = __builtin_amdgcn_mfma_f32_16x16x32_bf16(a0, b0, acc, 0,0,0);
      acc = __builtin_amdgcn_mfma_f32_16x16x32_bf16(a1, b1v, acc, 0,0,0);
      float bb = b1s[nt*16 + c];
      #pragma unroll
      for (int rg = 0; rg < 4; ++rg){
        float v = acc[rg] + bb;
        F1[(rw + quad*4 + rg)*136 + nt*16 + c] = f2us(gelu_f(v));
      }
    }
    // ff2 (same-wave LDS in-order)
    bf16x8 fa[4];
    #pragma unroll
    for (int ks = 0; ks < 4; ++ks)
      fa[ks] = *(const bf16x8*)&F1[(rw+c)*136 + ks*32 + quad*8];
    __syncthreads();   // all fa in regs before hs writes overwrite F1 region
    f32x4 ov[4];
    #pragma unroll
    for (int nt = 0; nt < 4; ++nt){
      f32x4 acc = {0,0,0,0};
      #pragma unroll
      for (int ks = 0; ks < 4; ++ks){
        bf16x8 b = *(const bf16x8*)&W2g[(nt*16+c)*136 + ks*32 + quad*8];
        acc = __builtin_amdgcn_mfma_f32_16x16x32_bf16(fa[ks], b, acc, 0,0,0);
      }
      ov[nt] = acc;
    }
    float r4[4][4];
    #pragma unroll
    for (int nt = 0; nt < 4; ++nt){
      int col = nt*16 + c;
      float bb = b2s[col];
      #pragma unroll
      for (int rg = 0; rg < 4; ++rg){
        float seqv = us2f(Xs[(rw + quad*4 + rg)*72 + col]);
        r4[nt][rg] = ov[nt][rg] + bb + seqv;
      }
    }
    float hval[4] = {0.f, 0.f, 0.f, 0.f};
    #pragma unroll
    for (int rg = 0; rg < 4; ++rg){
      float sm = r4[0][rg]+r4[1][rg]+r4[2][rg]+r4[3][rg];
      sm += __shfl_xor(sm,1); sm += __shfl_xor(sm,2);
      sm += __shfl_xor(sm,4); sm += __shfl_xor(sm,8);
      float mean = sm * (1.f/64.f);
      float d0=r4[0][rg]-mean, d1=r4[1][rg]-mean, d2=r4[2][rg]-mean, d3=r4[3][rg]-mean;
      float vs = d0*d0+d1*d1+d2*d2+d3*d3;
      vs += __shfl_xor(vs,1); vs += __shfl_xor(vs,2);
      vs += __shfl_xor(vs,4); vs += __shfl_xor(vs,8);
      float rinv = rsqrtf(vs*(1.f/64.f) + 1e-5f);
      #pragma unroll
      for (int nt = 0; nt < 4; ++nt){
        int col = nt*16 + c;
        hval[nt] += (r4[nt][rg] - mean) * rinv * l2w[col] + l2b[col];
      }
    }
    // h (16x64) as bf16 hi+lo planes for exact-ish MFMA classifier
    #pragma unroll
    for (int nt = 0; nt < 4; ++nt){
      float hv = hval[nt] * 0.25f;
      unsigned short hh = f2us(hv);
      float lo = hv - us2f(hh);
      hsH[(w*4 + quad)*72 + nt*16 + c] = hh;
      hsL[(w*4 + quad)*72 + nt*16 + c] = f2us(lo);
    }
    __syncthreads();
    // classifier: out(16x40) = h @ Wc^T via MFMA, waves 0-2 each own a 16-col tile
    if (w < 3){
      bf16x8 hA0 = *(const bf16x8*)&hsH[c*72 + quad*8];
      bf16x8 hA1 = *(const bf16x8*)&hsH[c*72 + 32 + quad*8];
      bf16x8 lA0 = *(const bf16x8*)&hsL[c*72 + quad*8];
      bf16x8 lA1 = *(const bf16x8*)&hsL[c*72 + 32 + quad*8];
      bf16x8 wB0 = *(const bf16x8*)&Wcg[(w*16 + c)*72 + quad*8];
      bf16x8 wB1 = *(const bf16x8*)&Wcg[(w*16 + c)*72 + 32 + quad*8];
      f32x4 acc = {0,0,0,0};
      acc = __builtin_amdgcn_mfma_f32_16x16x32_bf16(hA0, wB0, acc, 0,0,0);
      acc = __builtin_amdgcn_mfma_f32_16x16x32_bf16(hA1, wB1, acc, 0,0,0);
      acc = __builtin_amdgcn_mfma_f32_16x16x32_bf16(lA0, wB0, acc, 0,0,0);
      acc = __builtin_amdgcn_mfma_f32_16x16x32_bf16(lA1, wB1, acc, 0,0,0);
      int o = w*16 + c;
      if (o < OUTC){
        float bb = bcs[o];
        #pragma unroll
        for (int rg = 0; rg < 4; ++rg)
          out[(size_t)(g*16 + quad*4 + rg)*OUTC + o] = acc[rg] + bb;
      }
    }
  }
}

extern "C" void kernel_launch(void* const* d_in, const int* in_sizes, int n_in,
                              void* d_out, int out_size, void* d_ws, size_t ws_size,
                              hipStream_t stream) {
  const float* x    = (const float*)d_in[0];
  const int*   ei   = (const int*  )d_in[1];
  const float* Win  = (const float*)d_in[2];
  const float* bin  = (const float*)d_in[3];
  const float* sgW  = (const float*)d_in[4];
  const float* sgb  = (const float*)d_in[5];
  const float* Wqkv = (const float*)d_in[6];
  const float* bqkv = (const float*)d_in[7];
  const float* Wo   = (const float*)d_in[8];
  const float* bo   = (const float*)d_in[9];
  const float* W1   = (const float*)d_in[10];
  const float* b1   = (const float*)d_in[11];
  const float* W2   = (const float*)d_in[12];
  const float* b2   = (const float*)d_in[13];
  const float* ln1w = (const float*)d_in[14];
  const float* ln1b = (const float*)d_in[15];
  const float* ln2w = (const float*)d_in[16];
  const float* ln2b = (const float*)d_in[17];
  const float* Wc   = (const float*)d_in[18];
  const float* bc   = (const float*)d_in[19];

  char* ws = (char*)d_ws;
  float*          dinv    = (float*)(ws);                     // 400,000 B
  int*            cnt     = (int*  )(ws + 400128);            // 400,000 B (degree)
  unsigned short* wp      = (unsigned short*)(ws + 800256);   // 141,056 B (ends 941,312)
  int*            binFill = (int*)(ws + 941312);              // 1,564 B (own slot, no alias)
  unsigned short* tokB    = (unsigned short*)(ws + 943104);   // 4*N*64*2 = 51,200,000 B
  unsigned short* pb0     = (unsigned short*)(ws + 52143104); // 12,800,000 B
  unsigned short* pb1     = (unsigned short*)(ws + 64943104); // 12,800,000 B
  // Aliases (lifetimes disjoint):
  //  - binned (9.6 MB, packed int): tok slot 1; dead after k_buckh0 (bucket),
  //    slot1 first written by tok1 in k_tokgather (later)
  //  - srcb (25.6 MB): tok slots 2+3; dead after gather3, written by k_tok23 after
  int* binned = (int*)(tokB + (size_t)1*NN*64);
  int* srcb   = (int*)(tokB + (size_t)2*NN*64);

  // prep: {zero binFill || weight prepack}
  k_prep0<<<130, 256, 0, stream>>>(Win, sgW, Wqkv, Wo, W1, W2, Wc, wp, binFill);
  // CSR pass 1
  k_bin<<<512, 256, 0, stream>>>(ei, binFill, binned);
  // {CSR pass 2 || h0}:  tok0 -> slot0, p0 -> pb1
  k_buckh0<<<NBIN + GB, 256, 0, stream>>>(binFill, binned, srcb, cnt, dinv,
                                          x, wp, bin, tokB, pb1);
  // hop 1: p1 = S p0
  k_gather<<<GG, 256, 0, stream>>>(cnt, srcb, dinv, pb1, pb0);
  // {tok1 (from p1) || hop 2: p2 = S p1}
  k_tokgather<<<GB + GG, 256, 0, stream>>>(pb0, wp + WP_SG, sgb, tokB + (size_t)1*NN*64,
                                           cnt, srcb, dinv, pb0, pb1);
  // hop 3: p3 = S p2   (last srcb consumer)
  k_gather<<<GG, 256, 0, stream>>>(cnt, srcb, dinv, pb1, pb0);
  // {tok2 (from p2=pb1) || tok3 (from p3=pb0)}
  k_tok23<<<2*GB, 256, 0, stream>>>(pb1, wp + WP_SG + 4608, sgb + 64,  tokB + (size_t)2*NN*64,
                                    pb0, wp + WP_SG + 9216, sgb + 128, tokB + (size_t)3*NN*64);

  k_attn<<<2048, 256, 0, stream>>>(tokB, wp, bqkv, bo, ln1w, ln1b);
  k_ffn <<<2048, 256, 0, stream>>>(tokB, wp, b1, b2, ln2w, ln2b, bc, (float*)d_out);
}